// Round 4
// baseline (89.500 us; speedup 1.0000x reference)
//
#include <hip/hip_runtime.h>
#include <hip/hip_bf16.h>

#define B_    8
#define Q_    64
#define C_    512
#define HW_   256
#define E_    512
#define HATT_ 128
#define HMLP_ 512
#define NCLS_ 14
#define NLAB_ 64

typedef unsigned short u16;
typedef unsigned int   u32;
typedef __attribute__((ext_vector_type(8))) short short8;   // 8 bf16
typedef __attribute__((ext_vector_type(4))) float f32x4;

// ws layout (bytes):
//   GBp  @ 0       : 256x1024 f32  (l,cq)-partials of [gamma|beta]   1 MB
//   Dlp  @ 1048576 : 256x128  f32  (l,cq)-partials of beta@W_att_h 128 KB
//   WT   @ 1179648 : 128x512 bf16  W_att_h^T [h][c]                128 KB
//   W1bf @ 1310720 : 512x512 bf16  W_mlp1                          512 KB
//   fT   @ 1835008 : 8x256x512 bf16 feature^T [b][n][c]              2 MB
//   pP   @ 3932160 : 512x2x512 f32  attn-weighted f partials         2 MB
//   pA   @ 6029312 : 512x2 f32      attn-mass partials               4 KB
// total ~6.03 MB

__device__ __forceinline__ float gelu_fast(float x) {
    // gelu via A&S 7.1.26 erf approx (|erf err| < 1.5e-7); rcp/exp on trans pipe
    const float ax = fabsf(x);
    const float t  = __builtin_amdgcn_rcpf(1.0f + 0.3275911f * ax);
    const float p  = t * (0.254829592f +
                     t * (-0.284496736f +
                     t * (1.421413741f +
                     t * (-1.453152027f +
                     t * 1.061405429f))));
    const float e  = __expf(-x * x);
    const float er = copysignf(1.0f - p * e, x);
    return 0.5f * x * (1.0f + er);
}
__device__ __forceinline__ float sigmoid_(float x) {
    return 1.0f / (1.0f + __expf(-x));
}
__device__ __forceinline__ u16 f2bf(float x) {              // RNE f32->bf16
    u32 u = __float_as_uint(x);
    u32 r = (u + 0x7fffu + ((u >> 16) & 1u)) >> 16;
    return (u16)r;
}
__device__ __forceinline__ u32 cvt_pk_bf16(float lo, float hi) {
    u32 r;
    asm("v_cvt_pk_bf16_f32 %0, %1, %2" : "=v"(r) : "v"(lo), "v"(hi));
    return r;
}

// ---------------------------------------------------------------------------
// P0 (merged label-independent preps + GB partial GEMM), 592 blocks x 256 thr:
//  [0,256)   GBp[(l,cq)][j] = sum_{c in cq-slice} qt[l][c] W_film[c][j]
//  [256,272) WT[h][c] = bf16(W_att_h[c][h])
//  [272,528) fT[b][n][c] = bf16(feature[b][c][n])
//  [528,592) W1bf = bf16(W_mlp1)
// ---------------------------------------------------------------------------
__global__ __launch_bounds__(256) void prep_misc(
    const float* __restrict__ qt, const float* __restrict__ W_film,
    const float* __restrict__ W_att_h, const float* __restrict__ feature,
    const float* __restrict__ W_mlp1,
    float* __restrict__ GBp, u16* __restrict__ WT,
    u16* __restrict__ W1bf, u16* __restrict__ fT) {

    __shared__ __align__(16) char sm[16640];
    const int bid = blockIdx.x, t = threadIdx.x;

    if (bid < 256) {                       // ---- GB partials
        float* qrow = (float*)sm;          // 128 floats
        const int l = bid >> 2, cq = bid & 3;
        if (t < 128) qrow[t] = qt[l * E_ + cq * 128 + t];
        __syncthreads();
        const float* wp = W_film + (size_t)(cq * 128) * 1024 + t * 4;
        f32x4 a = {0.f, 0.f, 0.f, 0.f};
        #pragma unroll 8
        for (int c = 0; c < 128; ++c) {
            const float4 w = *(const float4*)(wp + (size_t)c * 1024);
            const float q = qrow[c];
            a.x += q * w.x; a.y += q * w.y; a.z += q * w.z; a.w += q * w.w;
        }
        *(f32x4*)&GBp[(size_t)bid * 1024 + t * 4] = a;
    } else if (bid < 272) {                // ---- WT transpose (bf16)
        float (*tile)[129] = (float(*)[129])sm;     // 32 x 129
        const int c0 = (bid - 256) * 32;
        const int cl = t >> 3, hq = t & 7;
        #pragma unroll
        for (int i = 0; i < 4; ++i) {
            const int h = hq * 16 + i * 4;
            *(float4*)&tile[cl][h] = *(const float4*)&W_att_h[(c0 + cl) * HATT_ + h];
        }
        __syncthreads();
        const int h = t >> 1, half_ = t & 1;
        u16 pk[16];
        #pragma unroll
        for (int i = 0; i < 16; ++i) pk[i] = f2bf(tile[half_ * 16 + i][h]);
        u16* dst = WT + (size_t)h * C_ + c0 + half_ * 16;
        *(uint4*)dst       = *(uint4*)pk;
        *(uint4*)(dst + 8) = *(uint4*)(pk + 8);
    } else if (bid < 528) {                // ---- fT transpose
        float (*tile)[65] = (float(*)[65])sm;       // 64 x 65
        const int bb = bid - 272;
        const int b = bb >> 5, c0 = ((bb >> 2) & 7) * 64, n0 = (bb & 3) * 64;
        const float* fb = feature + (size_t)b * C_ * HW_;
        const int cl = t >> 2, nq = t & 3;
        #pragma unroll
        for (int i = 0; i < 4; ++i) {
            float4 v = *(const float4*)&fb[(c0 + cl) * HW_ + n0 + nq * 16 + i * 4];
            tile[cl][nq * 16 + i * 4 + 0] = v.x;
            tile[cl][nq * 16 + i * 4 + 1] = v.y;
            tile[cl][nq * 16 + i * 4 + 2] = v.z;
            tile[cl][nq * 16 + i * 4 + 3] = v.w;
        }
        __syncthreads();
        const int nl = t >> 2, cqq = t & 3;
        u16 pk[16];
        #pragma unroll
        for (int k = 0; k < 16; ++k) pk[k] = f2bf(tile[cqq * 16 + k][nl]);
        u16* dst = fT + (size_t)(b * HW_ + n0 + nl) * C_ + c0 + cqq * 16;
        *(uint4*)dst       = *(uint4*)pk;
        *(uint4*)(dst + 8) = *(uint4*)(pk + 8);
    } else {                               // ---- W1 -> bf16
        const int b2 = bid - 528;
        #pragma unroll
        for (int k = 0; k < 2; ++k) {
            const int idx = (b2 * 512 + k * 256 + t) * 8;
            float4 v0 = *(const float4*)&W_mlp1[idx];
            float4 v1 = *(const float4*)&W_mlp1[idx + 4];
            u16 pk[8] = {f2bf(v0.x), f2bf(v0.y), f2bf(v0.z), f2bf(v0.w),
                         f2bf(v1.x), f2bf(v1.y), f2bf(v1.z), f2bf(v1.w)};
            *(uint4*)&W1bf[idx] = *(uint4*)pk;
        }
    }
}

// ---------------------------------------------------------------------------
// P1: Dl partials. 256 blocks (l, cq) x 128 thr:
//   Dlp[(l,cq)][h] = sum_{c in cq-slice} beta_l[c] W_att_h[c][h]
// beta recovered inline from GBp partials + b_film.
// ---------------------------------------------------------------------------
__global__ __launch_bounds__(128) void prep_dl(
    const float* __restrict__ b_film, const float* __restrict__ GBp,
    const float* __restrict__ W_att_h, float* __restrict__ Dlp) {
    __shared__ float beta_sh[128];
    const int bid = blockIdx.x, t = threadIdx.x;
    const int l = bid >> 2, cq = bid & 3;
    const int c = cq * 128 + t;
    beta_sh[t] = b_film[512 + c]
               + GBp[(size_t)(l * 4 + 0) * 1024 + 512 + c]
               + GBp[(size_t)(l * 4 + 1) * 1024 + 512 + c]
               + GBp[(size_t)(l * 4 + 2) * 1024 + 512 + c]
               + GBp[(size_t)(l * 4 + 3) * 1024 + 512 + c];
    __syncthreads();
    float a = 0.f;
    #pragma unroll 8
    for (int i = 0; i < 128; ++i)
        a += beta_sh[i] * W_att_h[(cq * 128 + i) * HATT_ + t];
    Dlp[(size_t)bid * 128 + t] = a;
}

// ---------------------------------------------------------------------------
// K_A: attn GEMM + pool partials. 1024 blocks = (b:8 XCD-major, q:64, nh:2),
// 256 thr (4 waves, 2x2 of 64x64). Per block: hidden-half (128n x 128h),
// K=512 in 8 supersteps of 64 (dbuf LDS B, on-the-fly gamma scale), fast-gelu
// epilogue -> attn(128) -> partial p[c], partial A -> ws. attn never hits HBM.
// ---------------------------------------------------------------------------
__global__ __launch_bounds__(256, 4) void attn_gemm(
    const int*   __restrict__ label_ids,
    const float* __restrict__ W_att_f, const float* __restrict__ b_att_f,
    const float* __restrict__ b_film,  const float* __restrict__ b_att_h,
    const float* __restrict__ GBp,     const float* __restrict__ Dlp,
    const u16*   __restrict__ WT,      const u16* __restrict__ fT,
    float* __restrict__ pP, float* __restrict__ pA) {

    __shared__ __align__(16) char big[32768];   // B dbuf 2x16KB; epilogue union
    __shared__ float gamma_s[C_];
    __shared__ float d_s[HATT_];
    __shared__ float wf_s[HATT_];

    const int t = threadIdx.x;
    const int idx = blockIdx.x;
    const int b = idx & 7, r = idx >> 3, q = r & 63, nh = r >> 6;
    const int bq = b * 64 + q, l = label_ids[bq];
    const int n0b = nh * 128;

    // gamma (inline GBp reduce), d, wf
    #pragma unroll
    for (int i = 0; i < 2; ++i) {
        const int c = t + i * 256;
        gamma_s[c] = b_film[c]
                   + GBp[(size_t)(l * 4 + 0) * 1024 + c]
                   + GBp[(size_t)(l * 4 + 1) * 1024 + c]
                   + GBp[(size_t)(l * 4 + 2) * 1024 + c]
                   + GBp[(size_t)(l * 4 + 3) * 1024 + c];
    }
    if (t < HATT_) {
        d_s[t] = b_att_h[t]
               + Dlp[(size_t)(l * 4 + 0) * 128 + t]
               + Dlp[(size_t)(l * 4 + 1) * 128 + t]
               + Dlp[(size_t)(l * 4 + 2) * 128 + t]
               + Dlp[(size_t)(l * 4 + 3) * 128 + t];
        wf_s[t] = W_att_f[t];
    }

    // staging geometry (BK=64 tile = 128h x 64c bf16 = 16 KB = 1024 granules):
    // gid = k*256+t -> LDS byte gid*16; h = gid>>3, slot = gid&7,
    // ck0 = (slot ^ (h&7))*8 elements.
    const int srow = t >> 3;                        // h = k*32 + srow
    const int sck  = ((t & 7) ^ (srow & 7)) * 8;

    const int lane = t & 63, w = t >> 6;
    const int wm = w >> 1, wc = w & 1;
    const int lr = lane & 15, lk = lane >> 4;
    const int n0w = wm * 64, hbase = wc * 64;
    const u16* fTb = fT + (size_t)b * HW_ * C_;

    const f32x4 zero = {0.f, 0.f, 0.f, 0.f};
    f32x4 acc[4][4];
    #pragma unroll
    for (int mi = 0; mi < 4; ++mi)
        #pragma unroll
        for (int ni = 0; ni < 4; ++ni) acc[mi][ni] = zero;

    uint4 wv[4];
    #define STAGE_LOAD(s_)                                                    \
        _Pragma("unroll")                                                     \
        for (int k = 0; k < 4; ++k)                                           \
            wv[k] = *(const uint4*)(WT + (size_t)(k * 32 + srow) * C_ +       \
                                    (s_) * 64 + sck);
    #define STAGE_WRITE(buf_, s_) {                                           \
        const float4 g0 = *(const float4*)&gamma_s[(s_) * 64 + sck];          \
        const float4 g1 = *(const float4*)&gamma_s[(s_) * 64 + sck + 4];      \
        _Pragma("unroll")                                                     \
        for (int k = 0; k < 4; ++k) {                                         \
            uint4 rr;                                                         \
            rr.x = cvt_pk_bf16(__uint_as_float(wv[k].x << 16) * g0.x,         \
                               __uint_as_float(wv[k].x & 0xffff0000u) * g0.y);\
            rr.y = cvt_pk_bf16(__uint_as_float(wv[k].y << 16) * g0.z,         \
                               __uint_as_float(wv[k].y & 0xffff0000u) * g0.w);\
            rr.z = cvt_pk_bf16(__uint_as_float(wv[k].z << 16) * g1.x,         \
                               __uint_as_float(wv[k].z & 0xffff0000u) * g1.y);\
            rr.w = cvt_pk_bf16(__uint_as_float(wv[k].w << 16) * g1.z,         \
                               __uint_as_float(wv[k].w & 0xffff0000u) * g1.w);\
            *(uint4*)(big + (buf_) * 16384 + (k * 256 + t) * 16) = rr;        \
        } }

    __syncthreads();                 // gamma_s ready
    STAGE_LOAD(0); STAGE_WRITE(0, 0);
    __syncthreads();

    for (int s = 0; s < 8; ++s) {
        const int buf = s & 1;
        if (s < 7) STAGE_LOAD(s + 1);
        #pragma unroll
        for (int ks = 0; ks < 2; ++ks) {
            const int ck = ks * 32 + lk * 8;
            short8 af[4];
            #pragma unroll
            for (int mi = 0; mi < 4; ++mi)
                af[mi] = *(const short8*)(fTb +
                    (size_t)(n0b + n0w + mi * 16 + lr) * C_ + s * 64 + ck);
            #pragma unroll
            for (int ni = 0; ni < 4; ++ni) {
                const int h = hbase + ni * 16 + lr;
                const short8 bv = *(const short8*)(big + buf * 16384 + h * 128
                                                   + ((ck * 2) ^ ((h & 7) << 4)));
                acc[0][ni] = __builtin_amdgcn_mfma_f32_16x16x32_bf16(af[0], bv, acc[0][ni], 0, 0, 0);
                acc[1][ni] = __builtin_amdgcn_mfma_f32_16x16x32_bf16(af[1], bv, acc[1][ni], 0, 0, 0);
                acc[2][ni] = __builtin_amdgcn_mfma_f32_16x16x32_bf16(af[2], bv, acc[2][ni], 0, 0, 0);
                acc[3][ni] = __builtin_amdgcn_mfma_f32_16x16x32_bf16(af[3], bv, acc[3][ni], 0, 0, 0);
            }
        }
        if (s < 7) STAGE_WRITE(buf ^ 1, s + 1);
        __syncthreads();
    }

    // epilogue scratch aliases big (B dbuf dead after final sync)
    float* attn_part = (float*)big;           // [2][128]
    float* attn_s    = (float*)(big + 2048);  // [128]

    // C/D frag: col(h) = lr, row(n) = lk*4 + j  within each 16x16
    #pragma unroll
    for (int mi = 0; mi < 4; ++mi) {
        #pragma unroll
        for (int j = 0; j < 4; ++j) {
            float sum = 0.f;
            #pragma unroll
            for (int ni = 0; ni < 4; ++ni) {
                const int h = hbase + ni * 16 + lr;
                sum += gelu_fast(acc[mi][ni][j] + d_s[h]) * wf_s[h];
            }
            sum += __shfl_xor(sum, 1);
            sum += __shfl_xor(sum, 2);
            sum += __shfl_xor(sum, 4);
            sum += __shfl_xor(sum, 8);
            if (lr == 0) attn_part[wc * 128 + n0w + mi * 16 + lk * 4 + j] = sum;
        }
    }
    __syncthreads();
    if (t < 128)
        attn_s[t] = sigmoid_(attn_part[t] + attn_part[128 + t] + b_att_f[0]);
    __syncthreads();
    if (t < 64) {
        float a = attn_s[t] + attn_s[t + 64];
        #pragma unroll
        for (int m = 1; m < 64; m <<= 1) a += __shfl_xor(a, m);
        if (t == 0) pA[bq * 2 + nh] = a;
    }

    // partial p: thread t owns c = 2t, 2t+1 over this block's 128 n's
    {
        float p0 = 0.f, p1 = 0.f;
        const u16* fp = fTb + (size_t)n0b * C_ + t * 2;
        #pragma unroll 8
        for (int n = 0; n < 128; ++n) {
            const u32 v = *(const u32*)(fp + (size_t)n * C_);
            const float a = attn_s[n];
            p0 += a * __uint_as_float(v << 16);
            p1 += a * __uint_as_float(v & 0xffff0000u);
        }
        float2 pv = {p0, p1};
        *(float2*)&pP[(size_t)(bq * 2 + nh) * 512 + t * 2] = pv;
    }
}

// ---------------------------------------------------------------------------
// K_B: pool-combine + MLP head. 256 blocks x 512 thr, 2 bq per block.
// pooled = (gamma*p + beta*A)/(A+eps); z = gelu(pooled@W1); out = z@W2 + b2.
// ---------------------------------------------------------------------------
__global__ __launch_bounds__(512) void mlp_head(
    const int*   __restrict__ label_ids,
    const float* __restrict__ b_film, const float* __restrict__ GBp,
    const float* __restrict__ b_mlp1, const float* __restrict__ W_mlp2,
    const float* __restrict__ b_mlp2, const float* __restrict__ pP,
    const float* __restrict__ pA,     const u16* __restrict__ W1bf,
    float* __restrict__ out) {

    __shared__ float pooled_s[2][C_];
    __shared__ float zred[2][2][HMLP_];
    __shared__ float z_s[2][HMLP_];
    __shared__ float red_s[32 * NCLS_];

    const int t = threadIdx.x;
    const int bq0 = blockIdx.x * 2;

    {   // pooled for both bq (each thread: one bqi, two c)
        const int bqi = t >> 8, cc = (t & 255) * 2;
        const int bq = bq0 + bqi, l = label_ids[bq];
        const float A = pA[bq * 2] + pA[bq * 2 + 1];
        const float inv = 1.0f / (A + 1e-8f);
        #pragma unroll
        for (int i = 0; i < 2; ++i) {
            const int c = cc + i;
            const float p = pP[(size_t)(bq * 2) * 512 + c]
                          + pP[(size_t)(bq * 2 + 1) * 512 + c];
            const float g  = b_film[c]
                           + GBp[(size_t)(l * 4 + 0) * 1024 + c]
                           + GBp[(size_t)(l * 4 + 1) * 1024 + c]
                           + GBp[(size_t)(l * 4 + 2) * 1024 + c]
                           + GBp[(size_t)(l * 4 + 3) * 1024 + c];
            const float be = b_film[512 + c]
                           + GBp[(size_t)(l * 4 + 0) * 1024 + 512 + c]
                           + GBp[(size_t)(l * 4 + 1) * 1024 + 512 + c]
                           + GBp[(size_t)(l * 4 + 2) * 1024 + 512 + c]
                           + GBp[(size_t)(l * 4 + 3) * 1024 + 512 + c];
            pooled_s[bqi][c] = (g * p + be * A) * inv;
        }
    }
    __syncthreads();

    {   // Phase C: z = pooled @ W1 (c-split x2, h-pair per thread, both bq)
        const int hp = t & 255, cg = t >> 8;
        float z00 = 0.f, z01 = 0.f, z10 = 0.f, z11 = 0.f;
        const u16* wp = W1bf + hp * 2;
        #pragma unroll 8
        for (int c = cg * 256; c < cg * 256 + 256; ++c) {
            const u32 v = *(const u32*)(wp + (size_t)c * HMLP_);
            const float w0 = __uint_as_float(v << 16);
            const float w1 = __uint_as_float(v & 0xffff0000u);
            const float pa = pooled_s[0][c], pb = pooled_s[1][c];
            z00 += pa * w0; z01 += pa * w1;
            z10 += pb * w0; z11 += pb * w1;
        }
        float2 a0 = {z00, z01}, a1 = {z10, z11};
        *(float2*)&zred[cg][0][hp * 2] = a0;
        *(float2*)&zred[cg][1][hp * 2] = a1;
    }
    __syncthreads();
    {
        const int bqi = t >> 8, h2 = (t & 255) * 2;
        #pragma unroll
        for (int i = 0; i < 2; ++i) {
            const int h = h2 + i;
            z_s[bqi][h] = gelu_fast(zred[0][bqi][h] + zred[1][bqi][h] + b_mlp1[h]);
        }
    }
    __syncthreads();

    #pragma unroll
    for (int bqi = 0; bqi < 2; ++bqi) {
        if (t < 448) {
            const int o = t % 14, seg = t / 14;
            float s = 0.f;
            #pragma unroll
            for (int k = 0; k < 16; ++k) {
                const int h = seg * 16 + k;
                s += z_s[bqi][h] * W_mlp2[h * NCLS_ + o];
            }
            red_s[seg * NCLS_ + o] = s;
        }
        __syncthreads();
        if (t < NCLS_) {
            float s = b_mlp2[t];
            #pragma unroll
            for (int seg = 0; seg < 32; ++seg) s += red_s[seg * NCLS_ + t];
            out[(bq0 + bqi) * NCLS_ + t] = s;
        }
        __syncthreads();
    }
}

// ---------------------------------------------------------------------------
extern "C" void kernel_launch(void* const* d_in, const int* in_sizes, int n_in,
                              void* d_out, int out_size, void* d_ws, size_t ws_size,
                              hipStream_t stream) {
    const float* feature   = (const float*)d_in[0];
    const int*   label_ids = (const int*)  d_in[1];
    const float* qt        = (const float*)d_in[2];
    const float* W_film    = (const float*)d_in[3];
    const float* b_film    = (const float*)d_in[4];
    const float* W_att_h   = (const float*)d_in[5];
    const float* b_att_h   = (const float*)d_in[6];
    const float* W_att_f   = (const float*)d_in[7];
    const float* b_att_f   = (const float*)d_in[8];
    const float* W_mlp1    = (const float*)d_in[9];
    const float* b_mlp1    = (const float*)d_in[10];
    const float* W_mlp2    = (const float*)d_in[11];
    const float* b_mlp2    = (const float*)d_in[12];
    float* out = (float*)d_out;

    char* wsb  = (char*)d_ws;
    float* GBp = (float*)wsb;                   //   1 MB
    float* Dlp = (float*)(wsb + 1048576);       // 128 KB
    u16*   WT  = (u16*)  (wsb + 1179648);       // 128 KB
    u16*   W1bf= (u16*)  (wsb + 1310720);       // 512 KB
    u16*   fTp = (u16*)  (wsb + 1835008);       //   2 MB
    float* pP  = (float*)(wsb + 3932160);       //   2 MB
    float* pA  = (float*)(wsb + 6029312);       //   4 KB

    hipLaunchKernelGGL(prep_misc, dim3(592), dim3(256), 0, stream,
                       qt, W_film, W_att_h, feature, W_mlp1, GBp, WT, W1bf, fTp);
    hipLaunchKernelGGL(prep_dl, dim3(256), dim3(128), 0, stream,
                       b_film, GBp, W_att_h, Dlp);
    hipLaunchKernelGGL(attn_gemm, dim3(1024), dim3(256), 0, stream,
                       label_ids, W_att_f, b_att_f, b_film, b_att_h,
                       GBp, Dlp, WT, fTp, pP, pA);
    hipLaunchKernelGGL(mlp_head, dim3(256), dim3(512), 0, stream,
                       label_ids, b_film, GBp, b_mlp1, W_mlp2, b_mlp2,
                       pP, pA, W1bf, out);
}